// Round 8
// baseline (81.392 us; speedup 1.0000x reference)
//
#include <hip/hip_runtime.h>

#define THRESH 1.0f
#define DECAY  0.5f

typedef float f32x4 __attribute__((ext_vector_type(4)));

constexpr int BLOCK = 256;
constexpr int NPT = 2;                      // neurons per thread
constexpr int TILE = BLOCK * NPT;           // 512 neurons / tile
constexpr int PAD = 12;                     // floats per neuron in LDS (48 B, 0 conflicts measured)

__global__ __launch_bounds__(BLOCK) void lif_kernel(const float* __restrict__ X,
                                                    float* __restrict__ S,
                                                    long long n_neurons) {
    __shared__ float lds[2][TILE * PAD];    // 48 KiB -> 3 blocks/CU, 12 waves/CU
    const int tid = threadIdx.x;
    const long long n_tiles  = (n_neurons + TILE - 1) / TILE;
    const long long total_f4 = n_neurons * 2;

    const f32x4* __restrict__ Xv = reinterpret_cast<const f32x4*>(X);
    f32x4* __restrict__ Sv = reinterpret_cast<f32x4*>(S);

    long long tile = blockIdx.x;
    if (tile >= n_tiles) return;

    f32x4 a[NPT], b[NPT];
    // Preload first tile into registers (plain loads: keep X L3-resident).
#pragma unroll
    for (int r = 0; r < NPT; ++r) {
        long long gn = tile * TILE + tid + r * BLOCK;
        if (gn < n_neurons) { a[r] = Xv[2 * gn]; b[r] = Xv[2 * gn + 1]; }
    }

    int cur = 0;
    while (true) {
        const long long next = tile + gridDim.x;

        // Compute recurrence from registers; spikes -> LDS[cur] (transposed).
#pragma unroll
        for (int r = 0; r < NPT; ++r) {
            int ln = tid + r * BLOCK;
            long long gn = tile * TILE + ln;
            if (gn < n_neurons) {
                float xv[8] = {a[r][0], a[r][1], a[r][2], a[r][3],
                               b[r][0], b[r][1], b[r][2], b[r][3]};
                float sv[8];
                float mem = 0.0f;
#pragma unroll
                for (int t = 0; t < 8; ++t) {
                    mem = mem * DECAY + xv[t];
                    bool fired = (mem >= THRESH);
                    sv[t] = fired ? 1.0f : 0.0f;
                    mem   = fired ? 0.0f : mem;      // v_cndmask
                }
                *reinterpret_cast<f32x4*>(&lds[cur][ln * PAD + 0]) = (f32x4){sv[0], sv[1], sv[2], sv[3]};
                *reinterpret_cast<f32x4*>(&lds[cur][ln * PAD + 4]) = (f32x4){sv[4], sv[5], sv[6], sv[7]};
            }
        }

        // Prefetch next tile BEFORE the barrier: these loads stay in flight
        // across the barrier and the entire NT-store phase (read/write overlap
        // within each wave, not just across blocks).
        if (next < n_tiles) {
#pragma unroll
            for (int r = 0; r < NPT; ++r) {
                long long gn = next * TILE + tid + r * BLOCK;
                if (gn < n_neurons) { a[r] = Xv[2 * gn]; b[r] = Xv[2 * gn + 1]; }
            }
        }

        __syncthreads();                             // one barrier per tile

        // Lane-contiguous NT stores: whole cachelines per wave instruction,
        // no partial-line amplification, write stream bypasses L3 so X stays
        // resident between graph replays.
        const long long base_f4 = tile * (long long)TILE * 2;
#pragma unroll
        for (int k = 0; k < 4; ++k) {
            int g = tid + k * BLOCK;
            long long gi = base_f4 + g;
            if (gi < total_f4) {
                int neuron = g >> 1;
                int e4 = (g & 1) * 4;
                f32x4 s = *reinterpret_cast<const f32x4*>(&lds[cur][neuron * PAD + e4]);
                __builtin_nontemporal_store(s, &Sv[gi]);
            }
        }

        if (next >= n_tiles) break;
        tile = next;
        cur ^= 1;   // double buffer: LDS[cur] not rewritten until 2 barriers later
    }
}

extern "C" void kernel_launch(void* const* d_in, const int* in_sizes, int n_in,
                              void* d_out, int out_size, void* d_ws, size_t ws_size,
                              hipStream_t stream) {
    const float* X = (const float*)d_in[0];
    float* S = (float*)d_out;
    long long n_elems   = (long long)in_sizes[0];
    long long n_neurons = n_elems / 8;   // T = 8, last (contiguous) axis

    long long n_tiles = (n_neurons + TILE - 1) / TILE;
    int grid = (int)(n_tiles < 2048 ? n_tiles : 2048);   // 16384 tiles -> 8 iters/block
    lif_kernel<<<grid, BLOCK, 0, stream>>>(X, S, n_neurons);
}

// Round 9
// 80.473 us; speedup vs baseline: 1.0114x; 1.0114x over previous
//
#include <hip/hip_runtime.h>

#define THRESH 1.0f
#define DECAY  0.5f

typedef float f32x4 __attribute__((ext_vector_type(4)));

constexpr int BLOCK = 256;
constexpr int NEUR_PER_THREAD = 2;
constexpr int TILE_NEURONS = BLOCK * NEUR_PER_THREAD;   // 512 neurons / tile
constexpr int PAD = 12;                                 // floats per neuron in LDS (48 B, 16B-aligned, 0 conflicts measured)

__global__ __launch_bounds__(BLOCK) void lif_kernel(const float* __restrict__ X,
                                                    float* __restrict__ S,
                                                    long long n_neurons) {
    __shared__ float lds[TILE_NEURONS * PAD];           // 24 KiB -> 6 blocks/CU
    const int tid = threadIdx.x;
    const long long tile = blockIdx.x;                  // exact grid: one tile per block
    const long long base_neuron = tile * TILE_NEURONS;
    const long long base_f4 = base_neuron * 2;
    const long long total_f4 = n_neurons * 2;

    const f32x4* __restrict__ Xv = reinterpret_cast<const f32x4*>(X);
    f32x4* __restrict__ Sv = reinterpret_cast<f32x4*>(S);

    // Phase 1: strided register loads (32B lane-stride, proven perf-neutral),
    // compute recurrence, write ONLY spikes into LDS (transposed layout).
#pragma unroll
    for (int r = 0; r < NEUR_PER_THREAD; ++r) {
        int ln = tid + r * BLOCK;                       // local neuron 0..511
        long long gn = base_neuron + ln;
        if (gn < n_neurons) {
            f32x4 a = Xv[gn * 2];                       // plain loads: keep X L3-resident
            f32x4 b = Xv[gn * 2 + 1];
            float xv[8] = {a[0], a[1], a[2], a[3], b[0], b[1], b[2], b[3]};
            float sv[8];
            float mem = 0.0f;
#pragma unroll
            for (int t = 0; t < 8; ++t) {
                mem = mem * DECAY + xv[t];
                bool fired = (mem >= THRESH);
                sv[t] = fired ? 1.0f : 0.0f;
                mem   = fired ? 0.0f : mem;             // v_cndmask
            }
            *reinterpret_cast<f32x4*>(&lds[ln * PAD + 0]) = (f32x4){sv[0], sv[1], sv[2], sv[3]};
            *reinterpret_cast<f32x4*>(&lds[ln * PAD + 4]) = (f32x4){sv[4], sv[5], sv[6], sv[7]};
        }
    }
    __syncthreads();                                    // the ONLY barrier

    // Phase 2: lane-contiguous NT stores — whole cachelines per wave
    // instruction (no partial-line amplification), bypassing L3 so the
    // write stream doesn't evict X between graph replays.
#pragma unroll
    for (int k = 0; k < 4; ++k) {
        int g = tid + k * BLOCK;                        // 0..1023 float4s in tile
        long long gi = base_f4 + g;
        if (gi < total_f4) {
            int neuron = g >> 1;
            int e4 = (g & 1) * 4;
            f32x4 s = *reinterpret_cast<const f32x4*>(&lds[neuron * PAD + e4]);
            __builtin_nontemporal_store(s, &Sv[gi]);
        }
    }
}

extern "C" void kernel_launch(void* const* d_in, const int* in_sizes, int n_in,
                              void* d_out, int out_size, void* d_ws, size_t ws_size,
                              hipStream_t stream) {
    const float* X = (const float*)d_in[0];
    float* S = (float*)d_out;
    long long n_elems   = (long long)in_sizes[0];
    long long n_neurons = n_elems / 8;   // T = 8, last (contiguous) axis

    long long n_tiles = (n_neurons + TILE_NEURONS - 1) / TILE_NEURONS;  // exact grid
    lif_kernel<<<(int)n_tiles, BLOCK, 0, stream>>>(X, S, n_neurons);
}